// Round 10
// baseline (452.258 us; speedup 1.0000x reference)
//
#include <hip/hip_runtime.h>
#include <cstdint>
#include <cstddef>

// Problem constants (match reference setup_inputs)
#define Bb   256
#define Tt   250
#define DIN  700
#define Hh   128
#define DOUT 20

// ---------------------------------------------------------------------------
// Phase 1: EXACT R0 gemm (218 us, VGPR 92, verified). Do not touch.
// ---------------------------------------------------------------------------
constexpr int BM  = 128;
constexpr int BK  = 20;
constexpr int BN  = 128;
constexpr int BMP = BM + 4;

__device__ __forceinline__ int bswz(int g) { return g ^ (g >> 3); }

__global__ __launch_bounds__(256, 2) void gemm_h1(const float* __restrict__ x,
                                                  const float* __restrict__ W1,
                                                  const float* __restrict__ b1,
                                                  float* __restrict__ H1) {
    __shared__ float Ast[BK][BMP];
    __shared__ float Bs[BK][BN];

    const int tid = threadIdx.x;
    const int tx  = tid & 15;
    const int ty  = tid >> 4;
    const int m0  = blockIdx.x * BM;

    const int c0 = bswz(tx * 2) * 4;
    const int c1 = bswz(tx * 2 + 1) * 4;

    float acc[8][8];
#pragma unroll
    for (int r = 0; r < 8; ++r)
#pragma unroll
        for (int c = 0; c < 8; ++c) acc[r][c] = 0.f;

    for (int k0 = 0; k0 < DIN; k0 += BK) {
#pragma unroll
        for (int idx = tid; idx < 640; idx += 256) {
            int row = idx / 5;
            int kq  = (idx - row * 5) * 4;
            const float4 v =
                *(const float4*)&x[(size_t)(m0 + row) * DIN + (k0 + kq)];
            Ast[kq + 0][row] = v.x;
            Ast[kq + 1][row] = v.y;
            Ast[kq + 2][row] = v.z;
            Ast[kq + 3][row] = v.w;
        }
#pragma unroll
        for (int idx = tid; idx < 640; idx += 256) {
            int kr = idx >> 5;
            int g  = idx & 31;
            *(float4*)&Bs[kr][bswz(g) * 4] =
                *(const float4*)&W1[(size_t)(k0 + kr) * BN + g * 4];
        }
        __syncthreads();

#pragma unroll
        for (int kk = 0; kk < BK; ++kk) {
            float a[8], bv[8];
            *(float4*)&a[0]  = *(const float4*)&Ast[kk][ty * 8];
            *(float4*)&a[4]  = *(const float4*)&Ast[kk][ty * 8 + 4];
            *(float4*)&bv[0] = *(const float4*)&Bs[kk][c0];
            *(float4*)&bv[4] = *(const float4*)&Bs[kk][c1];
#pragma unroll
            for (int r = 0; r < 8; ++r)
#pragma unroll
                for (int c = 0; c < 8; ++c)
                    acc[r][c] = fmaf(a[r], bv[c], acc[r][c]);
        }
        __syncthreads();
    }

    float bb[8];
#pragma unroll
    for (int c = 0; c < 8; ++c) bb[c] = b1[tx * 8 + c];

#pragma unroll
    for (int r = 0; r < 8; ++r) {
        size_t row = (size_t)(m0 + ty * 8 + r);
        float4 o0, o1;
        o0.x = acc[r][0] + bb[0]; o0.y = acc[r][1] + bb[1];
        o0.z = acc[r][2] + bb[2]; o0.w = acc[r][3] + bb[3];
        o1.x = acc[r][4] + bb[4]; o1.y = acc[r][5] + bb[5];
        o1.z = acc[r][6] + bb[6]; o1.w = acc[r][7] + bb[7];
        *(float4*)&H1[row * Hh + tx * 8]     = o0;
        *(float4*)&H1[row * Hh + tx * 8 + 4] = o1;
    }
}

// ---------------------------------------------------------------------------
// Phase 2: recurrence, wave-parallel cold pull.
// SESSION LEDGER LAW (R0-R9, 7 measurements): a recurrent pass reading COLD
// H1 with 1 wave/block costs 217-244us regardless of structure (ring, asm
// regs, plain-C, guards, preamble or not); the same pass over WARM (L2) H1
// costs 35us (R5 passes 1-11). Delivery/gather mechanics were never the
// lever -- the single-wave cold pull of 128KB/block (~12KB in flight/wave,
// ~180GB/s effective chip-wide) is the wall.
// Fix: one batch's H1 is 125KB -> fits LDS. 512 threads: all 8 waves
// cooperatively copy H1[b] -> LDS (coalesced float4; 2048 waves chip-wide
// => BW-bound pull, ~10-20us), barrier, wave 0 runs the EXACT R9-verified
// step code from static LDS (no ring/WAITV/chunks). Waves 1-7 park at the
// closing barrier. Gathers: EXACT R9 fused-asm (absmax 0.0 verified).
// Arithmetic and summation order bit-identical to R9 => absmax 0.0.
// ---------------------------------------------------------------------------

#define EXTR(K)                                                        \
    if (mlo) { K = (int)__ffsll(mlo) - 1; mlo &= mlo - 1ull; }         \
    else     { K = 64 + (int)__ffsll(mhi) - 1; mhi &= mhi - 1ull; }
#define EXTR2(K)                                                       \
    if (mlo)      { K = (int)__ffsll(mlo) - 1; mlo &= mlo - 1ull; }    \
    else if (mhi) { K = 64 + (int)__ffsll(mhi) - 1; mhi &= mhi - 1ull; }

// 8 dword loads from 4 row pointers (x at +0, y at +256B) and the retiring
// s_waitcnt fused in ONE asm block: destination regs are unobservable until
// retired -> no pending-register hazard (R7/R9-verified mechanism).
#define GATHER4(D0X, D0Y, D1X, D1Y, D2X, D2Y, D3X, D3Y, P0, P1, P2, P3)       \
    asm volatile("global_load_dword %0, %8, off\n\t"                          \
                 "global_load_dword %1, %8, off offset:256\n\t"               \
                 "global_load_dword %2, %9, off\n\t"                          \
                 "global_load_dword %3, %9, off offset:256\n\t"               \
                 "global_load_dword %4, %10, off\n\t"                         \
                 "global_load_dword %5, %10, off offset:256\n\t"              \
                 "global_load_dword %6, %11, off\n\t"                         \
                 "global_load_dword %7, %11, off offset:256\n\t"              \
                 "s_waitcnt vmcnt(0)"                                         \
                 : "=&v"(D0X), "=&v"(D0Y), "=&v"(D1X), "=&v"(D1Y),            \
                   "=&v"(D2X), "=&v"(D2Y), "=&v"(D3X), "=&v"(D3Y)             \
                 : "v"(P0), "v"(P1), "v"(P2), "v"(P3)                         \
                 : "memory");

__global__ __launch_bounds__(512) void recurrent(
    const float* __restrict__ H1,   const float* __restrict__ rcW1,
    const float* __restrict__ rcb1, const float* __restrict__ W2,
    const float* __restrict__ b2,   const float* __restrict__ rcW2,
    const float* __restrict__ rcb2, const float* __restrict__ W3,
    const float* __restrict__ b3,   float* __restrict__ out) {

    __shared__ __align__(16) float h1ls[Tt * Hh];   // 125 KB: full series

    const int tid = threadIdx.x;      // 0..511
    const int b   = blockIdx.x;

    // ---- cooperative load: H1[b] (128 KB) -> LDS, all 8 waves ----
    {
        const float4* __restrict__ src =
            (const float4*)(H1 + (size_t)b * Tt * Hh);
        float4* dst = (float4*)h1ls;
#pragma unroll 4
        for (int i = tid; i < (Tt * Hh / 4); i += 512) dst[i] = src[i];
    }
    __syncthreads();

    if (tid < 64) {
        const int lane = tid;

        const float rcb1x = rcb1[lane], rcb1y = rcb1[lane + 64];
        const float bb2x  = b2[lane]      + rcb2[lane];
        const float bb2y  = b2[lane + 64] + rcb2[lane + 64];

        float v1x = 0.f, v1y = 0.f, v2x = 0.f, v2y = 0.f;
        float cntx = 0.f, cnty = 0.f;
        float u1gx = 0.f, u1gy = 0.f;     // rcW1 gather (valid iff sp1)
        float u2gx = 0.f, u2gy = 0.f;     // rcW2 gather (valid iff sp2)
        bool  sp1 = false, sp2 = false;

        // 4-deep register pipeline (slot j holds step t, t%4==j), from LDS
        float h1xs[4], h1ys[4];
#pragma unroll
        for (int j = 0; j < 4; ++j) {
            h1xs[j] = h1ls[(j << 7) + lane];
            h1ys[j] = h1ls[(j << 7) + lane + 64];
        }

#define STEP(T, J)                                                            \
    {                                                                         \
        const int t_ = (T);                                                   \
        /* ---- LIF 1 (consume slot J, refill it for t+4 from LDS) ---- */    \
        float u1xv = h1xs[J] + rcb1x;                                         \
        float u1yv = h1ys[J] + rcb1y;                                         \
        if (sp1) { u1xv += u1gx; u1yv += u1gy; }                              \
        int tp = t_ + 4; tp = (tp < Tt) ? tp : (Tt - 1);                      \
        const float* rp_ = &h1ls[tp << 7];                                    \
        h1xs[J] = rp_[lane];                                                  \
        h1ys[J] = rp_[lane + 64];                                             \
        v1x = v1x + (u1xv - v1x) * 0.5f;                                      \
        v1y = v1y + (u1yv - v1y) * 0.5f;                                      \
        const bool s1x = (v1x >= 1.0f);                                       \
        const bool s1y = (v1y >= 1.0f);                                       \
        if (s1x) v1x = 0.f;                                                   \
        if (s1y) v1y = 0.f;                                                   \
        const unsigned long long a0 = __ballot((int)s1x);                     \
        const unsigned long long a1 = __ballot((int)s1y);                     \
        /* ---- layer-1 fanout: W2 + rcW1 from global, fused asm, 2 spike-    \
           indices per round, ascending k, left-fold (R9-verified) ---- */    \
        float uW2x = 0.f, uW2y = 0.f;                                         \
        sp1 = ((a0 | a1) != 0ull);                                            \
        if (sp1) {                                                            \
            float g1x = 0.f, g1y = 0.f;                                       \
            unsigned long long mlo = a0, mhi = a1;                            \
            while (mlo | mhi) {                                               \
                int k0; int k1 = -1;                                          \
                EXTR(k0) EXTR2(k1)                                            \
                const int kb = (k1 >= 0 ? k1 : k0);                           \
                const float* pw0 = W2   + ((size_t)k0 << 7) + lane;           \
                const float* pr0 = rcW1 + ((size_t)k0 << 7) + lane;           \
                const float* pw1 = W2   + ((size_t)kb << 7) + lane;           \
                const float* pr1 = rcW1 + ((size_t)kb << 7) + lane;           \
                float w0x, w0y, r0x, r0y, w1x, w1y, r1x, r1y;                 \
                GATHER4(w0x, w0y, r0x, r0y, w1x, w1y, r1x, r1y,               \
                        pw0, pr0, pw1, pr1)                                   \
                uW2x += w0x; uW2y += w0y; g1x += r0x; g1y += r0y;             \
                if (k1 >= 0) {                                                \
                    uW2x += w1x; uW2y += w1y; g1x += r1x; g1y += r1y;         \
                }                                                             \
            }                                                                 \
            u1gx = g1x; u1gy = g1y;                                           \
        }                                                                     \
        /* ---- LIF 2 (apply prev-step rcW2 gather under sp2 guard) ---- */   \
        float u2xv = bb2x + uW2x;                                             \
        float u2yv = bb2y + uW2y;                                             \
        if (sp2) { u2xv += u2gx; u2yv += u2gy; }                              \
        v2x = v2x + (u2xv - v2x) * 0.5f;                                      \
        v2y = v2y + (u2yv - v2y) * 0.5f;                                      \
        const bool s2x = (v2x >= 1.0f);                                       \
        const bool s2y = (v2y >= 1.0f);                                       \
        if (s2x) v2x = 0.f;                                                   \
        if (s2y) v2y = 0.f;                                                   \
        cntx += s2x ? 1.f : 0.f;                                              \
        cnty += s2y ? 1.f : 0.f;                                              \
        const unsigned long long c0m = __ballot((int)s2x);                    \
        const unsigned long long c1m = __ballot((int)s2y);                    \
        /* ---- layer-2 rcW2 gather: EXACT R7/R9 fused asm, ascending k */    \
        sp2 = ((c0m | c1m) != 0ull);                                          \
        if (sp2) {                                                            \
            float sx = 0.f, sy = 0.f;                                         \
            unsigned long long mlo = c0m, mhi = c1m;                          \
            while (mlo | mhi) {                                               \
                int k0; int k1 = -1; int k2 = -1; int k3 = -1;                \
                EXTR(k0) EXTR2(k1) EXTR2(k2) EXTR2(k3)                        \
                const float* p0 = rcW2 + ((size_t)k0 << 7) + lane;            \
                const float* p1 =                                             \
                    rcW2 + ((size_t)(k1 >= 0 ? k1 : k0) << 7) + lane;         \
                const float* p2 =                                             \
                    rcW2 + ((size_t)(k2 >= 0 ? k2 : k0) << 7) + lane;         \
                const float* p3 =                                             \
                    rcW2 + ((size_t)(k3 >= 0 ? k3 : k0) << 7) + lane;         \
                float d0x, d0y, d1x, d1y, d2x, d2y, d3x, d3y;                 \
                GATHER4(d0x, d0y, d1x, d1y, d2x, d2y, d3x, d3y,               \
                        p0, p1, p2, p3)                                       \
                sx += d0x; sy += d0y;                                         \
                if (k1 >= 0) { sx += d1x; sy += d1y; }                        \
                if (k2 >= 0) { sx += d2x; sy += d2y; }                        \
                if (k3 >= 0) { sx += d3x; sy += d3y; }                        \
            }                                                                 \
            u2gx = sx; u2gy = sy;                                             \
        }                                                                     \
    }

        // Main loop: 62 quads (t=0..247), then tail 248,249.
#pragma unroll 1
        for (int g = 0; g < 62; ++g) {
            const int t = g << 2;
            STEP(t + 0, 0)
            STEP(t + 1, 1)
            STEP(t + 2, 2)
            STEP(t + 3, 3)
        }
        STEP(248, 0)
        STEP(249, 1)
#undef STEP

        // stash counts in LDS (t=0 slots long consumed; safe to overwrite)
        h1ls[lane]      = cntx;
        h1ls[lane + 64] = cnty;
    }
    __syncthreads();

    // ---- readout: out[b] = cnt2 @ W3 + T*b3 ----
    if (tid < DOUT) {
        float o = (float)Tt * b3[tid];
#pragma unroll 8
        for (int k = 0; k < Hh; ++k) o += h1ls[k] * W3[k * DOUT + tid];
        out[b * DOUT + tid] = o;
    }
}

// ---------------------------------------------------------------------------
extern "C" void kernel_launch(void* const* d_in, const int* in_sizes, int n_in,
                              void* d_out, int out_size, void* d_ws, size_t ws_size,
                              hipStream_t stream) {
    const float* x    = (const float*)d_in[0];
    const float* W1   = (const float*)d_in[1];
    const float* b1   = (const float*)d_in[2];
    const float* rcW1 = (const float*)d_in[3];
    const float* rcb1 = (const float*)d_in[4];
    const float* W2   = (const float*)d_in[5];
    const float* b2   = (const float*)d_in[6];
    const float* rcW2 = (const float*)d_in[7];
    const float* rcb2 = (const float*)d_in[8];
    const float* W3   = (const float*)d_in[9];
    const float* b3   = (const float*)d_in[10];

    float* out = (float*)d_out;
    float* H1  = (float*)d_ws;   // 64000 x 128 f32 = 32.77 MB

    gemm_h1<<<(Bb * Tt) / BM, 256, 0, stream>>>(x, W1, b1, H1);
    recurrent<<<Bb, 512, 0, stream>>>(H1, rcW1, rcb1, W2, b2, rcW2, rcb2, W3,
                                      b3, out);
}